// Round 7
// baseline (378.172 us; speedup 1.0000x reference)
//
#include <hip/hip_runtime.h>
#include <hip/hip_fp16.h>
#include <stdint.h>

typedef _Float16 f16x8 __attribute__((ext_vector_type(8)));
typedef _Float16 f16x4 __attribute__((ext_vector_type(4)));
typedef _Float16 f16x2 __attribute__((ext_vector_type(2)));
typedef float f32x4 __attribute__((ext_vector_type(4)));
typedef float f32x16 __attribute__((ext_vector_type(16)));

#define B_ 2
#define S_ 2048
#define NE 2048
#define NH 32
#define NKV 8
#define HD 64
#define NTOK (B_ * S_)   // 4096
#define QKVN 3072

// pack two f32 -> f16x2 (cvt_pkrtz returns __fp16x2; bit-cast to our type)
__device__ __forceinline__ f16x2 pk(float a, float b) {
  return __builtin_bit_cast(f16x2, __builtin_amdgcn_cvt_pkrtz(a, b));
}

// ---------------- async global->LDS (16B per lane, lane-ordered dest) -------
__device__ __forceinline__ void gld_lds16(void* lds, const void* g) {
  __builtin_amdgcn_global_load_lds(
      (const __attribute__((address_space(1))) void*)g,
      (__attribute__((address_space(3))) void*)lds, 16, 0, 0);
}

// ---------------- fp32 -> fp16 elementwise (x) ------------------------------
__global__ void conv_x_kernel(const float* __restrict__ x,
                              _Float16* __restrict__ xo, int n2) {
  int i = blockIdx.x * 256 + threadIdx.x;
  if (i < n2) {
    float2 v = ((const float2*)x)[i];
    f16x2 h;
    h.x = (_Float16)v.x;
    h.y = (_Float16)v.y;
    ((f16x2*)xo)[i] = h;
  }
}

// ------------- transpose + convert: dst[(rowoff+n)*ldd + k] = src[k][n] -----
__global__ void tconv_kernel(const float* __restrict__ src,
                             _Float16* __restrict__ dst,
                             int srcN, int rowoff, int ldd) {
  __shared__ float tile[32][33];
  int n0 = blockIdx.x * 32, k0 = blockIdx.y * 32;
  int tx = threadIdx.x, ty = threadIdx.y;
  for (int i = ty; i < 32; i += 8)
    tile[i][tx] = src[(size_t)(k0 + i) * srcN + n0 + tx];
  __syncthreads();
  for (int i = ty; i < 32; i += 8)
    dst[(size_t)(rowoff + n0 + i) * ldd + k0 + tx] = (_Float16)tile[tx][i];
}

// ------------- GEMM: C(MxN) = A(MxK,f16) * Bt(NxK,f16)^T, fp32 accum --------
// 128x128 tile, 256 threads (4 waves, each 64x64), BK=32, 16x16x32 f16 MFMA.
template <int OUT_F32>
__global__ __launch_bounds__(256, 2) void gemm_bt(
    const _Float16* __restrict__ A, const _Float16* __restrict__ Bt,
    void* __restrict__ Cout, int M, int N, int K) {
  __shared__ _Float16 As[128 * 32];
  __shared__ _Float16 Bs[128 * 32];
  const int tid = threadIdx.x;
  const int wave = tid >> 6, lane = tid & 63;
  const int qd = lane >> 4, ln = lane & 15;
  const int m0 = blockIdx.y * 128, n0 = blockIdx.x * 128;
  const int wm = (wave >> 1) * 64, wn = (wave & 1) * 64;

  f32x4 acc[4][4] = {};

  const int srow = (lane >> 2);        // 0..15 within a 16-row chunk
  const int scol = (lane & 3) * 8;     // element offset (16B per lane)

  for (int k0 = 0; k0 < K; k0 += 32) {
    __syncthreads();
#pragma unroll
    for (int it = 0; it < 2; ++it) {
      int r = wave * 32 + it * 16 + srow;
      gld_lds16(&As[(wave * 32 + it * 16) * 32],
                A + (size_t)(m0 + r) * K + k0 + scol);
      gld_lds16(&Bs[(wave * 32 + it * 16) * 32],
                Bt + (size_t)(n0 + r) * K + k0 + scol);
    }
    __syncthreads();
    f16x8 a[4], b[4];
#pragma unroll
    for (int mt = 0; mt < 4; ++mt)
      a[mt] = *(const f16x8*)&As[(wm + mt * 16 + ln) * 32 + qd * 8];
#pragma unroll
    for (int nt = 0; nt < 4; ++nt)
      b[nt] = *(const f16x8*)&Bs[(wn + nt * 16 + ln) * 32 + qd * 8];
#pragma unroll
    for (int mt = 0; mt < 4; ++mt)
#pragma unroll
      for (int nt = 0; nt < 4; ++nt)
        acc[mt][nt] =
            __builtin_amdgcn_mfma_f32_16x16x32_f16(a[mt], b[nt], acc[mt][nt], 0, 0, 0);
  }

  // epilogue: C/D layout col=lane&15, row=(lane>>4)*4+reg
#pragma unroll
  for (int mt = 0; mt < 4; ++mt) {
    int row = m0 + wm + mt * 16 + qd * 4;
#pragma unroll
    for (int nt = 0; nt < 4; ++nt) {
      int col = n0 + wn + nt * 16 + ln;
#pragma unroll
      for (int r = 0; r < 4; ++r) {
        if (OUT_F32)
          ((float*)Cout)[(size_t)(row + r) * N + col] = acc[mt][nt][r];
        else
          ((_Float16*)Cout)[(size_t)(row + r) * N + col] =
              (_Float16)acc[mt][nt][r];
      }
    }
  }
}

// ------------- RoPE + scatter (Q, K only) -----------------------------------
__global__ void rope_scatter_kernel(const _Float16* __restrict__ qkv,
                                    const float* __restrict__ fcos,
                                    const float* __restrict__ fsin,
                                    _Float16* __restrict__ Qb,
                                    _Float16* __restrict__ Kb) {
  const float QSC = 0.125f * 1.44269504088896f;
  int idx = blockIdx.x * 256 + threadIdx.x;  // < NTOK * 1280
  int t = idx / 1280;
  int col = (idx - t * 1280) * 2;
  int b = t >> 11, s = t & 2047;
  float v0 = (float)qkv[(size_t)t * QKVN + col];
  float v1 = (float)qkv[(size_t)t * QKVN + col + 1];
  _Float16* dst;
  size_t off;
  int d;
  float sc;
  if (col < 2048) {
    int h = col >> 6;
    d = col & 63;
    dst = Qb;
    off = ((size_t)(b * NH + h) * S_ + s) * HD + d;
    sc = QSC;
  } else {
    int cc = col - 2048;
    int h = cc >> 6;
    d = cc & 63;
    dst = Kb;
    off = ((size_t)(b * NKV + h) * S_ + s) * HD + d;
    sc = 1.0f;
  }
  float c = fcos[s * 32 + (d >> 1)], sn = fsin[s * 32 + (d >> 1)];
  f16x2 o;
  o.x = (_Float16)((v0 * c - v1 * sn) * sc);
  o.y = (_Float16)((v0 * sn + v1 * c) * sc);
  *(f16x2*)(dst + off) = o;
}

// ------------- V transpose: qkv cols [2560,3072) -> Vtg (B,KV,HD,S) ---------
__global__ void vtrans_kernel(const _Float16* __restrict__ qkv,
                              _Float16* __restrict__ Vtg) {
  __shared__ _Float16 tile[64][65];
  int t0 = blockIdx.x * 64;
  int kv = blockIdx.y, b = blockIdx.z;
  int tid = threadIdx.x;
  for (int slot = tid; slot < 4096; slot += 256) {
    int r = slot >> 6, c = slot & 63;  // r = token, c = dim
    tile[r][c] = qkv[(size_t)(b * S_ + t0 + r) * QKVN + 2560 + kv * 64 + c];
  }
  __syncthreads();
  size_t base = ((size_t)(b * NKV + kv) * HD) * S_;
  for (int slot = tid; slot < 4096; slot += 256) {
    int d = slot >> 6, r = slot & 63;
    Vtg[base + (size_t)d * S_ + t0 + r] = tile[r][d];
  }
}

// ------------- flash attention (causal, GQA, S^T + intra-block split-K) -----
// grid (16, NH, B): block bx does q-tiles (31-bx) then (bx), 64 q-rows each.
// 256 threads = 4 waves = 2 wave-PAIRS: pair 0 (w0,w1) computes EVEN k-tiles,
// pair 1 (w2,w3) ODD k-tiles, each with a private 16KB K/V LDS region ->
// 4 blocks/CU x 4 waves = 4 waves/SIMD of latency hiding. Fixed-shift softmax
// makes partials additive: pair 1 dumps accO/lsum via LDS (stride-33 overlay,
// conflict-free) and pair 0 combines + stores. P stays in registers
// (cvt_pkrtz + shfl_xor(32)); K/V XOR-swizzled; reg-prefetch one tile ahead.
__global__ __launch_bounds__(256, 4) void attn_kernel(
    const _Float16* __restrict__ Qb, const _Float16* __restrict__ Kb,
    const _Float16* __restrict__ Vtg, _Float16* __restrict__ Ob) {
  constexpr float M_SHIFT = 10.0f;
  __shared__ _Float16 smem[4 * 64 * 64];  // [pair][{K,V}][64*64] = 32 KB
  __shared__ float lsx[128];
  const int tid = threadIdx.x;
  const int wave = tid >> 6;       // 0..3
  const int pair = wave >> 1;      // key-split group
  const int wq = wave & 1;         // q-row half within pair
  const int lane = tid & 63;
  const int mrow = lane & 31;
  const bool half = (lane >> 5) != 0;
  const int h = blockIdx.y, b = blockIdx.z;
  const int kvh = h >> 2;

  _Float16* Ksp = smem + pair * 8192;
  _Float16* Vsp = Ksp + 4096;
  float* cb = (float*)smem;  // combine overlay: 128 rows x 33 f32 = 16.9 KB

  const _Float16* Qh = Qb + ((size_t)(b * NH + h) * S_) * HD;
  const _Float16* Kh = Kb + ((size_t)(b * NKV + kvh) * S_) * HD;
  const _Float16* Vh = Vtg + ((size_t)(b * NKV + kvh) * HD) * S_;

  const int ptid = tid & 127;  // pair-local thread id
  const int sr = ptid >> 3;    // 0..15 (base row of 4 strided staging rows)
  const int scc = ptid & 7;    // 16B chunk index
  const int swz = (scc ^ (sr & 7)) * 8;  // (sr+16i)&7 == sr&7

#pragma unroll
  for (int pass = 0; pass < 2; ++pass) {
    const int qt = pass ? blockIdx.x : (31 - blockIdx.x);
    const int q0 = qt * 64;
    const int nkt = qt + 1;         // 64-key tiles covering [0, q0+64)
    const int NI = (nkt + 1) >> 1;  // iterations per pair

    const int qrow = q0 + wq * 32 + mrow;
    f16x8 aq[4];  // Q[qrow][kk*16 + half*8 + 0..7] — B operand for S^T
#pragma unroll
    for (int kk = 0; kk < 4; ++kk)
      aq[kk] = *(const f16x8*)(Qh + (size_t)qrow * HD + kk * 16 +
                               (half ? 8 : 0));

    f32x16 accO[2] = {};
    float lsum = 0.f;

    // stage this pair's first tile (clamped for pair 1 when nkt == 1)
    const int t0 = (pair < nkt) ? pair : (nkt - 1);
    f16x8 kp[4], vp[4];
#pragma unroll
    for (int i = 0; i < 4; ++i) {
      kp[i] = *(const f16x8*)(Kh + (size_t)(t0 * 64 + sr + i * 16) * HD +
                              scc * 8);
      vp[i] = *(const f16x8*)(Vh + (size_t)(sr + i * 16) * S_ + t0 * 64 +
                              scc * 8);
    }
#pragma unroll
    for (int i = 0; i < 4; ++i) {
      *(f16x8*)&Ksp[(sr + i * 16) * 64 + swz] = kp[i];
      *(f16x8*)&Vsp[(sr + i * 16) * 64 + swz] = vp[i];
    }

    for (int it = 0; it < NI; ++it) {
      __syncthreads();  // staged writes visible
      const int kt = 2 * it + pair;
      const bool valid = kt < nkt;  // wave-uniform
      if (it + 1 < NI) {
        const int tn0 = 2 * (it + 1) + pair;
        const int tn = (tn0 < nkt) ? tn0 : (nkt - 1);
#pragma unroll
        for (int i = 0; i < 4; ++i) {
          kp[i] = *(const f16x8*)(Kh + (size_t)(tn * 64 + sr + i * 16) * HD +
                                  scc * 8);
          vp[i] = *(const f16x8*)(Vh + (size_t)(sr + i * 16) * S_ + tn * 64 +
                                  scc * 8);
        }
      }

      if (valid) {
        // S^T = K Q^T: lane col = q, reg rows = keys; acc pre-loaded with -M
        f32x16 s[2];
#pragma unroll
        for (int nt = 0; nt < 2; ++nt)
#pragma unroll
          for (int r = 0; r < 16; ++r) s[nt][r] = -M_SHIFT;
#pragma unroll
        for (int kk = 0; kk < 4; ++kk) {
          int c = kk * 2 + (half ? 1 : 0);
#pragma unroll
          for (int nt = 0; nt < 2; ++nt) {
            int krow = nt * 32 + mrow;
            f16x8 bk = *(const f16x8*)&Ksp[krow * 64 + ((c ^ (krow & 7)) * 8)];
            s[nt] = __builtin_amdgcn_mfma_f32_32x32x16_f16(bk, aq[kk], s[nt],
                                                           0, 0, 0);
          }
        }

        // p = exp2(s); only the diagonal tile needs masking (key > qrow)
        const bool edge = (kt == nkt - 1);
        float pf[2][16];
#pragma unroll
        for (int nt = 0; nt < 2; ++nt)
#pragma unroll
          for (int r = 0; r < 16; ++r) {
            int key = kt * 64 + nt * 32 + (r & 3) + 8 * (r >> 2) +
                      (half ? 4 : 0);
            float p = exp2f(s[nt][r]);
            if (edge && key > qrow) p = 0.f;
            lsum += p;
            pf[nt][r] = p;
          }

        // pack to f16x2: P2[nt][c][u] = (p[4c+2u], p[4c+2u+1])
        f16x2 P2[2][4][2];
#pragma unroll
        for (int nt = 0; nt < 2; ++nt)
#pragma unroll
          for (int c = 0; c < 4; ++c)
#pragma unroll
            for (int u = 0; u < 2; ++u)
              P2[nt][c][u] =
                  pk(pf[nt][4 * c + 2 * u], pf[nt][4 * c + 2 * u + 1]);

        // O^T += V^T P^T: build P B-frag per 16-key step via shfl_xor(32)
#pragma unroll
        for (int s4 = 0; s4 < 4; ++s4) {
          const int ntp = s4 >> 1;
          const int gA = (2 * s4) & 3, gB = (2 * s4 + 1) & 3;
          f16x2 own0 = half ? P2[ntp][gB][0] : P2[ntp][gA][0];
          f16x2 own1 = half ? P2[ntp][gB][1] : P2[ntp][gA][1];
          f16x2 snd0 = half ? P2[ntp][gA][0] : P2[ntp][gB][0];
          f16x2 snd1 = half ? P2[ntp][gA][1] : P2[ntp][gB][1];
          f16x2 rcv0 = __builtin_bit_cast(
              f16x2, __shfl_xor(__builtin_bit_cast(int, snd0), 32));
          f16x2 rcv1 = __builtin_bit_cast(
              f16x2, __shfl_xor(__builtin_bit_cast(int, snd1), 32));
          union {
            f16x2 h2[4];
            f16x8 h8;
          } bp;
          bp.h2[0] = half ? rcv0 : own0;  // keys j=0..3 come from half 0
          bp.h2[1] = half ? rcv1 : own1;
          bp.h2[2] = half ? own0 : rcv0;  // keys j=4..7 come from half 1
          bp.h2[3] = half ? own1 : rcv1;
          const int c = 2 * s4 + (half ? 1 : 0);
#pragma unroll
          for (int ntd = 0; ntd < 2; ++ntd) {
            int drow = ntd * 32 + mrow;
            f16x8 bv = *(const f16x8*)&Vsp[drow * 64 + ((c ^ (drow & 7)) * 8)];
            accO[ntd] = __builtin_amdgcn_mfma_f32_32x32x16_f16(
                bv, bp.h8, accO[ntd], 0, 0, 0);
          }
        }
      }

      __syncthreads();  // this pair done reading Ksp/Vsp
      if (it + 1 < NI) {
#pragma unroll
        for (int i = 0; i < 4; ++i) {
          *(f16x8*)&Ksp[(sr + i * 16) * 64 + swz] = kp[i];
          *(f16x8*)&Vsp[(sr + i * 16) * 64 + swz] = vp[i];
        }
      }
    }

    // ---- combine pair 1 partials into pair 0 (additive: fixed shift) ----
    if (pair == 1) {
      float* my = cb + (wq * 64 + lane) * 33;
#pragma unroll
      for (int nt = 0; nt < 2; ++nt)
#pragma unroll
        for (int r = 0; r < 16; ++r) my[nt * 16 + r] = accO[nt][r];
      lsx[wq * 64 + lane] = lsum;
    }
    __syncthreads();
    if (pair == 0) {
      const float* my = cb + (wq * 64 + lane) * 33;
#pragma unroll
      for (int nt = 0; nt < 2; ++nt)
#pragma unroll
        for (int r = 0; r < 16; ++r) accO[nt][r] += my[nt * 16 + r];
      lsum += lsx[wq * 64 + lane];
    }
    __syncthreads();  // cb reads done before next pass overwrites smem

    if (pair == 0) {
      // epilogue: O^T C-layout — lane col = q, reg rows = d. 8B packed stores.
      float tot = lsum + __shfl_xor(lsum, 32);
      float inv = 1.f / tot;
      size_t base = ((size_t)(b * S_) + qrow) * NE + h * HD;
#pragma unroll
      for (int ntd = 0; ntd < 2; ++ntd)
#pragma unroll
        for (int rq = 0; rq < 4; ++rq) {
          int d0 = ntd * 32 + 8 * rq + (half ? 4 : 0);
          union {
            f16x2 h2[2];
            f16x4 h4;
          } o;
          o.h2[0] =
              pk(accO[ntd][4 * rq + 0] * inv, accO[ntd][4 * rq + 1] * inv);
          o.h2[1] =
              pk(accO[ntd][4 * rq + 2] * inv, accO[ntd][4 * rq + 3] * inv);
          *(f16x4*)(Ob + base + d0) = o.h4;
        }
    }
  }
}

// ---------------------------------------------------------------------------
extern "C" void kernel_launch(void* const* d_in, const int* in_sizes, int n_in,
                              void* d_out, int out_size, void* d_ws,
                              size_t ws_size, hipStream_t stream) {
  const float* x = (const float*)d_in[0];
  const float* wq = (const float*)d_in[1];
  const float* wk = (const float*)d_in[2];
  const float* wv = (const float*)d_in[3];
  const float* wo = (const float*)d_in[4];
  const float* fcos = (const float*)d_in[5];
  const float* fsin = (const float*)d_in[6];

  char* ws = (char*)d_ws;
  _Float16* xb = (_Float16*)(ws);                      // 16.78 MB
  _Float16* wqkv_t = (_Float16*)(ws + 16777216);       // 12.58 MB
  _Float16* wo_t = (_Float16*)(ws + 29360128);         // 8.39 MB
  _Float16* qkv = (_Float16*)(ws + 37748736);          // 25.17 MB
  _Float16* Qb = (_Float16*)(ws + 62914560);           // 16.78 MB
  _Float16* Kb = (_Float16*)(ws + 79691776);           // 4.19 MB
  _Float16* Vb = (_Float16*)(ws + 83886080);           // 4.19 MB (B,KV,HD,S)
  _Float16* Ob = (_Float16*)(ws + 88080384);           // 16.78 MB; total 104.9 MB

  // 1. convert x to fp16
  conv_x_kernel<<<16384, 256, 0, stream>>>(x, xb, (NTOK * NE) / 2);

  // 2. transpose-convert weights into B^T (N x K) layouts
  dim3 tb(32, 8);
  tconv_kernel<<<dim3(64, 64), tb, 0, stream>>>(wq, wqkv_t, 2048, 0, 2048);
  tconv_kernel<<<dim3(16, 64), tb, 0, stream>>>(wk, wqkv_t, 512, 2048, 2048);
  tconv_kernel<<<dim3(16, 64), tb, 0, stream>>>(wv, wqkv_t, 512, 2560, 2048);
  tconv_kernel<<<dim3(64, 64), tb, 0, stream>>>(wo, wo_t, 2048, 0, 2048);

  // 3. fused QKV projection: (4096 x 2048) @ (2048 x 3072) -> f16
  gemm_bt<0><<<dim3(QKVN / 128, NTOK / 128), 256, 0, stream>>>(
      xb, wqkv_t, qkv, NTOK, QKVN, NE);

  // 4a. RoPE + scatter Q/K (Q pre-scaled); 4b. transpose V to (B,KV,HD,S)
  rope_scatter_kernel<<<(NTOK * 1280) / 256, 256, 0, stream>>>(qkv, fcos, fsin,
                                                               Qb, Kb);
  vtrans_kernel<<<dim3(S_ / 64, NKV, B_), 256, 0, stream>>>(qkv, Vb);

  // 5. causal flash attention (paired 64-row q-tiles, intra-block split-K)
  attn_kernel<<<dim3(16, NH, B_), 256, 0, stream>>>(Qb, Kb, Vb, Ob);

  // 6. output projection -> fp32 d_out
  gemm_bt<1><<<dim3(NE / 128, NTOK / 128), 256, 0, stream>>>(
      Ob, wo_t, d_out, NTOK, NE, NE);
}